// Round 1
// baseline (517.792 us; speedup 1.0000x reference)
//
#include <hip/hip_runtime.h>
#include <hip/hip_bf16.h>
#include <math.h>

typedef unsigned long long u64;
typedef unsigned int u32;

#define A_TOTAL 24564
#define NCLS 80
#define NIMG 4
#define NPRE 2000
#define NLV 7
#define HBUCKETS 1024
#define BEXP_BASE 0x3CA3
#define BLK_PER_IMG 386

__device__ __constant__ int c_lvstart[NLV] = {0,16384,22528,24064,24448,24544,24560};
__device__ __constant__ int c_lvlen[NLV]   = {16384,6144,1536,384,96,16,4};
__device__ __constant__ int c_klv[NLV]     = {1000,1000,1000,1000,1000,1000,320};

// ---- workspace layout (bytes) ----
#define WS_HIST      0          // 28*1024*4 = 114688
#define WS_MCOUNT    114688     // 28*4
#define WS_BCOUNT    114800     // 28*4
#define WS_ZERO_END  114912
#define WS_CUT       114912     // 28*8
#define WS_MAIN      115136     // 28*1024*8
#define WS_BND       344512     // 28*4096*8
#define WS_CAND      1262016    // 4*2000*8
#define WS_BOXES     1326016    // 4*2000*16
#define WS_CLS       1454016    // 4*2000*4
#define WS_SCORE     1486016    // 4*2000*4
#define WS_MASK      1518016    // 4*2000*32*8
#define WS_REMV      3566016    // 4*32*8

__device__ inline u64 shfl_u64(u64 v, int src) {
  int lo = __shfl((int)(u32)(v & 0xFFFFFFFFULL), src);
  int hi = __shfl((int)(u32)(v >> 32), src);
  return ((u64)(u32)hi << 32) | (u32)lo;
}

// softmax over 81 logits, one wave per anchor. lane -> class lane (s0) and
// class 64+lane (s1, lane<16). Class 80 (background) joins max/sum only.
// Thresholded at 0.02 (zeros below). MUST be the single code path used by
// both the histogram and compact kernels so bits match exactly.
__device__ inline void compute_scores(const float* __restrict__ base, int lane,
                                      float& s0, float& s1) {
  float x0 = base[lane];
  float x1 = (lane < 17) ? base[64 + lane] : -3.0e38f;
  float m = fmaxf(x0, x1);
#pragma unroll
  for (int o = 32; o; o >>= 1) m = fmaxf(m, __shfl_xor(m, o));
  float e0 = expf(x0 - m);
  float e1 = (lane < 17) ? expf(x1 - m) : 0.0f;
  float t = e0 + e1;
#pragma unroll
  for (int o = 32; o; o >>= 1) t += __shfl_xor(t, o);
  s0 = e0 / t;
  s1 = (lane < 16) ? (e1 / t) : 0.0f;
  s0 = (s0 > 0.02f) ? s0 : 0.0f;
  s1 = (s1 > 0.02f) ? s1 : 0.0f;
}

__device__ inline int score_bucket(u32 bits) {
  int b = (int)(bits >> 16) - BEXP_BASE;
  return b < 0 ? 0 : (b > HBUCKETS - 1 ? HBUCKETS - 1 : b);
}

// block -> (img, level, anchor range); 64 anchors/block, level-partitioned grid
__device__ inline void block_map(int bx, int& img, int& l, int& a0, int& aend) {
  img = bx / BLK_PER_IMG;
  int b = bx % BLK_PER_IMG;
  int bloc;
  if (b < 256)      { l = 0; bloc = b; }
  else if (b < 352) { l = 1; bloc = b - 256; }
  else if (b < 376) { l = 2; bloc = b - 352; }
  else if (b < 382) { l = 3; bloc = b - 376; }
  else if (b < 384) { l = 4; bloc = b - 382; }
  else if (b < 385) { l = 5; bloc = b - 384; }
  else              { l = 6; bloc = b - 385; }
  a0 = c_lvstart[l] + bloc * 64;
  int ae = c_lvstart[l] + c_lvlen[l];
  aend = (a0 + 64 < ae) ? a0 + 64 : ae;
}

__global__ __launch_bounds__(256) void k_hist(const float* __restrict__ logits,
                                              u32* __restrict__ histG) {
  __shared__ u32 lh[HBUCKETS];
  int tid = threadIdx.x;
  for (int b = tid; b < HBUCKETS; b += 256) lh[b] = 0;
  __syncthreads();
  int img, l, a0, aend;
  block_map(blockIdx.x, img, l, a0, aend);
  int wid = tid >> 6, lane = tid & 63;
  for (int a = a0 + wid; a < aend; a += 4) {
    const float* base = logits + ((size_t)img * A_TOTAL + a) * 81;
    float s0, s1;
    compute_scores(base, lane, s0, s1);
    if (s0 > 0.0f) atomicAdd(&lh[score_bucket(__float_as_uint(s0))], 1u);
    if (s1 > 0.0f) atomicAdd(&lh[score_bucket(__float_as_uint(s1))], 1u);
  }
  __syncthreads();
  u32* hseg = histG + (size_t)(img * NLV + l) * HBUCKETS;
  for (int b = tid; b < HBUCKETS; b += 256) {
    u32 v = lh[b];
    if (v) atomicAdd(&hseg[b], v);
  }
}

__global__ __launch_bounds__(64) void k_cut(const u32* __restrict__ histG,
                                            int2* __restrict__ cutG) {
  int seg = blockIdx.x;  // 28 segs
  int lane = threadIdx.x;
  __shared__ u32 h[HBUCKETS];
  for (int b = lane; b < HBUCKETS; b += 64) h[b] = histG[(size_t)seg * HBUCKETS + b];
  __syncthreads();
  if (lane == 0) {
    int k = c_klv[seg % NLV];
    int total = 0;
    for (int b = 0; b < HBUCKETS; ++b) total += h[b];
    int2 r;
    if (total <= k) { r.x = -1; r.y = 0; }
    else {
      int cum = 0; r.x = 0; r.y = k;
      for (int b = HBUCKETS - 1; b >= 0; --b) {
        int c = (int)h[b];
        if (cum + c >= k) { r.x = b; r.y = k - cum; break; }
        cum += c;
      }
    }
    cutG[seg] = r;
  }
}

__device__ inline void emit_entry(float s, int a, int cls, int2 ct, int seg,
                                  u64* mainG, u32* mcount, u64* bndG, u32* bcount) {
  if (s <= 0.0f) return;
  u32 bits = __float_as_uint(s);
  int bk = score_bucket(bits);
  u64 key = ((u64)bits << 32) | (u64)(0xFFFFFFFFu - (u32)(a * NCLS + cls));
  if (ct.x < 0 || bk > ct.x) {
    u32 p = atomicAdd(&mcount[seg], 1u);
    if (p < 1024) mainG[(size_t)seg * 1024 + p] = key;
  } else if (bk == ct.x) {
    u32 p = atomicAdd(&bcount[seg], 1u);
    if (p < 4096) bndG[(size_t)seg * 4096 + p] = key;
  }
}

__global__ __launch_bounds__(256) void k_compact(const float* __restrict__ logits,
                                                 const int2* __restrict__ cutG,
                                                 u64* __restrict__ mainG, u32* __restrict__ mcount,
                                                 u64* __restrict__ bndG, u32* __restrict__ bcount) {
  int img, l, a0, aend;
  block_map(blockIdx.x, img, l, a0, aend);
  int seg = img * NLV + l;
  int2 ct = cutG[seg];
  int tid = threadIdx.x;
  int wid = tid >> 6, lane = tid & 63;
  for (int a = a0 + wid; a < aend; a += 4) {
    const float* base = logits + ((size_t)img * A_TOTAL + a) * 81;
    float s0, s1;
    compute_scores(base, lane, s0, s1);
    emit_entry(s0, a, lane, ct, seg, mainG, mcount, bndG, bcount);
    if (lane < 16) emit_entry(s1, a, 64 + lane, ct, seg, mainG, mcount, bndG, bcount);
  }
}

__device__ inline void bitonic_desc(u64* s, int n) {
  for (int k = 2; k <= n; k <<= 1)
    for (int j = k >> 1; j > 0; j >>= 1) {
      __syncthreads();
      for (int i = threadIdx.x; i < n; i += blockDim.x) {
        int l = i ^ j;
        if (l > i) {
          u64 a = s[i], b = s[l];
          if (((i & k) == 0) ? (a < b) : (a > b)) { s[i] = b; s[l] = a; }
        }
      }
    }
  __syncthreads();
}

// refine boundary bucket: top-k' appended to main list -> exact per-level top-k
__global__ __launch_bounds__(1024) void k_bsort(const int2* __restrict__ cutG,
                                                const u64* __restrict__ bndG,
                                                const u32* __restrict__ bcount,
                                                u64* __restrict__ mainG, u32* __restrict__ mcount) {
  int seg = blockIdx.x;
  int2 ct = cutG[seg];
  if (ct.x < 0) return;
  __shared__ u64 s[4096];
  int m = (int)bcount[seg]; if (m > 4096) m = 4096;
  int tid = threadIdx.x;
  for (int t = tid; t < 4096; t += 1024)
    s[t] = (t < m) ? bndG[(size_t)seg * 4096 + t] : 0ULL;
  bitonic_desc(s, 4096);
  int kp = ct.y; if (kp > m) kp = m;
  int base = (int)mcount[seg];
  for (int t = tid; t < kp; t += 1024) {
    int p = base + t;
    if (p < 1024) mainG[(size_t)seg * 1024 + p] = s[t];
  }
  if (tid == 0) {
    int nb = base + kp;
    mcount[seg] = (u32)(nb > 1024 ? 1024 : nb);
  }
}

// per-image: gather <=7168 capped candidates, sort desc, emit top-2000 keys
__global__ __launch_bounds__(1024) void k_gsort(const u64* __restrict__ mainG,
                                                const u32* __restrict__ mcount,
                                                u64* __restrict__ cand) {
  int img = blockIdx.x;
  int tid = threadIdx.x;
  __shared__ u64 s[8192];  // 64 KiB
  int cnt[NLV], off[NLV];
  int tot = 0;
#pragma unroll
  for (int l = 0; l < NLV; ++l) {
    int c = (int)mcount[img * NLV + l];
    if (c > 1024) c = 1024;
    cnt[l] = c; off[l] = tot; tot += c;
  }
#pragma unroll
  for (int l = 0; l < NLV; ++l)
    for (int t = tid; t < cnt[l]; t += 1024)
      s[off[l] + t] = mainG[(size_t)(img * NLV + l) * 1024 + t];
  for (int t = tot + tid; t < 8192; t += 1024) s[t] = 0ULL;
  __syncthreads();
  bitonic_desc(s, 8192);
  for (int t = tid; t < NPRE; t += 1024) cand[(size_t)img * NPRE + t] = s[t];
}

__global__ __launch_bounds__(256) void k_decode(const u64* __restrict__ cand,
                                                const float4* __restrict__ priors,
                                                const float4* __restrict__ reg,
                                                float4* __restrict__ boxesG,
                                                int* __restrict__ clsG,
                                                float* __restrict__ scoreG) {
  int g = blockIdx.x * 256 + threadIdx.x;
  if (g >= NIMG * NPRE) return;
  int img = g / NPRE;
  u64 key = cand[g];
  float4 bx = make_float4(0.f, 0.f, 0.f, 0.f);
  int c = -1;
  float sc = 0.f;
  if (key != 0ULL) {
    sc = __uint_as_float((u32)(key >> 32));
    u32 flat = 0xFFFFFFFFu - (u32)(key & 0xFFFFFFFFULL);
    int a = (int)(flat / NCLS);
    c = (int)(flat % NCLS);
    float4 p = priors[a];
    float4 r = reg[(size_t)img * A_TOTAL + a];
    float cx = p.x + (r.x * 0.1f) * p.z;
    float cy = p.y + (r.y * 0.1f) * p.w;
    float w = p.z * expf(r.z * 0.2f);
    float h = p.w * expf(r.w * 0.2f);
    bx.x = fminf(fmaxf(cx - w * 0.5f, 0.f), 512.f);
    bx.y = fminf(fmaxf(cy - h * 0.5f, 0.f), 512.f);
    bx.z = fminf(fmaxf(cx + w * 0.5f, 0.f), 512.f);
    bx.w = fminf(fmaxf(cy + h * 0.5f, 0.f), 512.f);
  }
  boxesG[g] = bx;
  clsG[g] = c;
  scoreG[g] = sc;
}

// suppression bitmask: row i, bit j set iff j>i, same class, IoU>0.45
__global__ __launch_bounds__(256) void k_mask(const float4* __restrict__ boxesG,
                                              const int* __restrict__ clsG,
                                              u64* __restrict__ maskG) {
  __shared__ float4 lb[NPRE];
  __shared__ int lc[NPRE];
  int img = blockIdx.x / 500;
  int rb = (blockIdx.x % 500) * 4;
  for (int t = threadIdx.x; t < NPRE; t += 256) {
    lb[t] = boxesG[(size_t)img * NPRE + t];
    lc[t] = clsG[(size_t)img * NPRE + t];
  }
  __syncthreads();
  int w = threadIdx.x >> 6, lane = threadIdx.x & 63;
  int i = rb + w;
  float4 bi = lb[i];
  int ci = lc[i];
  float ai = (bi.z - bi.x) * (bi.w - bi.y);
  u64* mrow = maskG + ((size_t)img * NPRE + i) * 32;
  for (int ch = 0; ch < 32; ++ch) {
    int j = ch * 64 + lane;
    bool pred = false;
    if (j < NPRE && j > i) {
      if (lc[j] == ci) {
        float4 bj = lb[j];
        float xx1 = fmaxf(bi.x, bj.x), yy1 = fmaxf(bi.y, bj.y);
        float xx2 = fminf(bi.z, bj.z), yy2 = fminf(bi.w, bj.w);
        float ww = fmaxf(xx2 - xx1, 0.f), hh = fmaxf(yy2 - yy1, 0.f);
        float inter = ww * hh;
        float aj = (bj.z - bj.x) * (bj.w - bj.y);
        float iou = inter / fmaxf(ai + aj - inter, 1e-6f);
        pred = iou > 0.45f;
      }
    }
    u64 word = __ballot(pred);
    if (lane == 0) mrow[ch] = word;
  }
}

// greedy serial scan; one wave per image; lane w<32 owns remv word w.
// Register double-buffered 16-row tiles hide load latency.
__global__ __launch_bounds__(64) void k_scan(const u64* __restrict__ maskG,
                                             u64* __restrict__ remvG) {
  int img = blockIdx.x;
  int lane = threadIdx.x;
  int wl = lane & 31;
  const u64* M = maskG + (size_t)img * NPRE * 32;
  u64 remv = 0;
  u64 cur[16], nxt[16];
#pragma unroll
  for (int r = 0; r < 16; ++r) cur[r] = M[(size_t)r * 32 + wl];
  for (int t = 0; t < 125; ++t) {
    if (t < 124) {
#pragma unroll
      for (int r = 0; r < 16; ++r) nxt[r] = M[(size_t)((t + 1) * 16 + r) * 32 + wl];
    }
#pragma unroll
    for (int r = 0; r < 16; ++r) {
      int i = t * 16 + r;
      u64 rm = shfl_u64(remv, i >> 6);
      if (!((rm >> (i & 63)) & 1ULL)) remv |= cur[r];
    }
#pragma unroll
    for (int r = 0; r < 16; ++r) cur[r] = nxt[r];
  }
  if (lane < 32) remvG[(size_t)img * 32 + lane] = remv;
}

// final: kept (in order = desc score) -> slots; zero-score slots get smallest
// suppressed indices ascending (jax top_k stability); fc NOT zeroed.
__global__ __launch_bounds__(256) void k_final(const u64* __restrict__ remvG,
                                               const float4* __restrict__ boxesG,
                                               const int* __restrict__ clsG,
                                               const float* __restrict__ scoreG,
                                               float* __restrict__ out) {
  int img = blockIdx.x;
  int tid = threadIdx.x;
  __shared__ u64 rw[32];
  __shared__ int kpref[257];
  __shared__ unsigned short K[NPRE], S[NPRE];
  if (tid < 32) rw[tid] = remvG[(size_t)img * 32 + tid];
  __syncthreads();
  int base = tid * 8;
  bool kb[8];
  int cnt = 0;
#pragma unroll
  for (int e = 0; e < 8; ++e) {
    int i = base + e;
    bool kept = false;
    if (i < NPRE) kept = !((rw[i >> 6] >> (i & 63)) & 1ULL);
    kb[e] = kept;
    cnt += kept ? 1 : 0;
  }
  kpref[tid + 1] = cnt;
  if (tid == 0) kpref[0] = 0;
  __syncthreads();
  if (tid == 0) {
    int acc = 0;
    for (int t = 1; t <= 256; ++t) { acc += kpref[t]; kpref[t] = acc; }
  }
  __syncthreads();
  int nK = kpref[256];
  int kp = kpref[tid];
  int sp = base - kpref[tid];
#pragma unroll
  for (int e = 0; e < 8; ++e) {
    int i = base + e;
    if (i < NPRE) {
      if (kb[e]) K[kp++] = (unsigned short)i;
      else S[sp++] = (unsigned short)i;
    }
  }
  __syncthreads();
  if (tid < 200) {
    int limit = nK < 200 ? nK : 200;
    float fv;
    float4 fb;
    int fc;
    if (tid < limit) {
      int idx = K[tid];
      fv = scoreG[(size_t)img * NPRE + idx];
      fb = boxesG[(size_t)img * NPRE + idx];
      fc = clsG[(size_t)img * NPRE + idx];
    } else {
      int idx = S[tid - nK];
      fv = 0.f;
      fb = make_float4(0.f, 0.f, 0.f, 0.f);
      fc = clsG[(size_t)img * NPRE + idx];
    }
    float* fbo = out + (size_t)img * 800 + tid * 4;
    fbo[0] = fb.x; fbo[1] = fb.y; fbo[2] = fb.z; fbo[3] = fb.w;
    out[3200 + (size_t)img * 200 + tid] = fv;
    out[4000 + (size_t)img * 200 + tid] = (float)fc;
  }
}

extern "C" void kernel_launch(void* const* d_in, const int* in_sizes, int n_in,
                              void* d_out, int out_size, void* d_ws, size_t ws_size,
                              hipStream_t stream) {
  const float* logits = (const float*)d_in[0];
  const float4* reg = (const float4*)d_in[1];
  const float4* priors = (const float4*)d_in[2];
  char* ws = (char*)d_ws;
  u32* hist = (u32*)(ws + WS_HIST);
  u32* mcount = (u32*)(ws + WS_MCOUNT);
  u32* bcount = (u32*)(ws + WS_BCOUNT);
  int2* cut = (int2*)(ws + WS_CUT);
  u64* mainL = (u64*)(ws + WS_MAIN);
  u64* bndL = (u64*)(ws + WS_BND);
  u64* cand = (u64*)(ws + WS_CAND);
  float4* boxes = (float4*)(ws + WS_BOXES);
  int* cls = (int*)(ws + WS_CLS);
  float* score = (float*)(ws + WS_SCORE);
  u64* mask = (u64*)(ws + WS_MASK);
  u64* remv = (u64*)(ws + WS_REMV);

  hipMemsetAsync(d_ws, 0, WS_ZERO_END, stream);
  k_hist<<<NIMG * BLK_PER_IMG, 256, 0, stream>>>(logits, hist);
  k_cut<<<28, 64, 0, stream>>>(hist, cut);
  k_compact<<<NIMG * BLK_PER_IMG, 256, 0, stream>>>(logits, cut, mainL, mcount, bndL, bcount);
  k_bsort<<<28, 1024, 0, stream>>>(cut, bndL, bcount, mainL, mcount);
  k_gsort<<<NIMG, 1024, 0, stream>>>(mainL, mcount, cand);
  k_decode<<<(NIMG * NPRE + 255) / 256, 256, 0, stream>>>(cand, priors, reg, boxes, cls, score);
  k_mask<<<NIMG * 500, 256, 0, stream>>>(boxes, cls, mask);
  k_scan<<<NIMG, 64, 0, stream>>>(mask, remv);
  k_final<<<NIMG, 256, 0, stream>>>(remv, boxes, cls, score, (float*)d_out);
}

// Round 2
// 249.543 us; speedup vs baseline: 2.0750x; 2.0750x over previous
//
#include <hip/hip_runtime.h>
#include <hip/hip_bf16.h>
#include <math.h>

typedef unsigned long long u64;
typedef unsigned int u32;

#define A_TOTAL 24564
#define NCLS 80
#define NIMG 4
#define NPRE 2000
#define NLV 7
#define HBUCKETS 1024
#define BEXP_BASE 0x3CA3
#define BLK_PER_IMG 386

__device__ __constant__ int c_lvstart[NLV] = {0,16384,22528,24064,24448,24544,24560};
__device__ __constant__ int c_lvlen[NLV]   = {16384,6144,1536,384,96,16,4};
__device__ __constant__ int c_klv[NLV]     = {1000,1000,1000,1000,1000,1000,320};

// ---- workspace layout (bytes) ----
#define WS_HIST      0          // 28*1024*4 = 114688
#define WS_MCOUNT    114688     // 28*4
#define WS_BCOUNT    114800     // 28*4
#define WS_ZERO_END  114912
#define WS_MAIN      115136     // 28*1024*8
#define WS_BND       344512     // 28*4096*8
#define WS_BOXES     1326016    // 4*2000*16
#define WS_CLS       1454016    // 4*2000*4
#define WS_SCORE     1486016    // 4*2000*4
#define WS_MASK      1518016    // 4*2000*32*8

__device__ inline u64 shfl_u64(u64 v, int src) {
  int lo = __shfl((int)(u32)(v & 0xFFFFFFFFULL), src);
  int hi = __shfl((int)(u32)(v >> 32), src);
  return ((u64)(u32)hi << 32) | (u32)lo;
}

// softmax over 81 logits, one wave per anchor. Single code path for both the
// histogram and compact kernels so score bits match exactly.
__device__ inline void compute_scores(const float* __restrict__ base, int lane,
                                      float& s0, float& s1) {
  float x0 = base[lane];
  float x1 = (lane < 17) ? base[64 + lane] : -3.0e38f;
  float m = fmaxf(x0, x1);
#pragma unroll
  for (int o = 32; o; o >>= 1) m = fmaxf(m, __shfl_xor(m, o));
  float e0 = expf(x0 - m);
  float e1 = (lane < 17) ? expf(x1 - m) : 0.0f;
  float t = e0 + e1;
#pragma unroll
  for (int o = 32; o; o >>= 1) t += __shfl_xor(t, o);
  s0 = e0 / t;
  s1 = (lane < 16) ? (e1 / t) : 0.0f;
  s0 = (s0 > 0.02f) ? s0 : 0.0f;
  s1 = (s1 > 0.02f) ? s1 : 0.0f;
}

__device__ inline int score_bucket(u32 bits) {
  int b = (int)(bits >> 16) - BEXP_BASE;
  return b < 0 ? 0 : (b > HBUCKETS - 1 ? HBUCKETS - 1 : b);
}

// One full wave finds (cut bucket, count-in-bucket) for top-k over a 1024-bin
// histogram h (global or LDS). Deterministic: same h,k -> same result.
__device__ inline void wave_find_cut(const u32* __restrict__ h, int k, int lane,
                                     int& cx, int& cy) {
  u32 s = 0;
#pragma unroll
  for (int i = 0; i < 16; ++i) s += h[lane * 16 + i];
  u32 S = s;  // inclusive suffix-sum across lanes: S[l] = sum_{m>=l} s[m]
#pragma unroll
  for (int o = 1; o < 64; o <<= 1) {
    u32 t = (u32)__shfl_down((int)S, o);
    if (lane + o < 64) S += t;
  }
  u32 total = (u32)__shfl((int)S, 0);
  if (total <= (u32)k) { cx = -1; cy = 0; return; }
  u64 bm = __ballot(S >= (u32)k);
  int L0 = 63 - (int)__clzll((long long)bm);
  u32 Sup = (u32)__shfl_down((int)S, 1);
  if (lane == 63) Sup = 0;
  int rcx = 0, rcy = 0;
  if (lane == L0) {
    u32 cum = Sup;  // count of entries in buckets >= 16*(L0+1)
    for (int i = 15; i >= 0; --i) {
      u32 c = h[lane * 16 + i];
      if (cum + c >= (u32)k) { rcx = lane * 16 + i; rcy = k - (int)cum; break; }
      cum += c;
    }
  }
  cx = __shfl(rcx, L0);
  cy = __shfl(rcy, L0);
}

// block -> (img, level, anchor range); 64 anchors/block, level-partitioned grid
__device__ inline void block_map(int bx, int& img, int& l, int& a0, int& aend) {
  img = bx / BLK_PER_IMG;
  int b = bx % BLK_PER_IMG;
  int bloc;
  if (b < 256)      { l = 0; bloc = b; }
  else if (b < 352) { l = 1; bloc = b - 256; }
  else if (b < 376) { l = 2; bloc = b - 352; }
  else if (b < 382) { l = 3; bloc = b - 376; }
  else if (b < 384) { l = 4; bloc = b - 382; }
  else if (b < 385) { l = 5; bloc = b - 384; }
  else              { l = 6; bloc = b - 385; }
  a0 = c_lvstart[l] + bloc * 64;
  int ae = c_lvstart[l] + c_lvlen[l];
  aend = (a0 + 64 < ae) ? a0 + 64 : ae;
}

__global__ __launch_bounds__(256) void k_hist(const float* __restrict__ logits,
                                              u32* __restrict__ histG) {
  __shared__ u32 lh[HBUCKETS];
  int tid = threadIdx.x;
  for (int b = tid; b < HBUCKETS; b += 256) lh[b] = 0;
  __syncthreads();
  int img, l, a0, aend;
  block_map(blockIdx.x, img, l, a0, aend);
  int wid = tid >> 6, lane = tid & 63;
  for (int a = a0 + wid; a < aend; a += 4) {
    const float* base = logits + ((size_t)img * A_TOTAL + a) * 81;
    float s0, s1;
    compute_scores(base, lane, s0, s1);
    if (s0 > 0.0f) atomicAdd(&lh[score_bucket(__float_as_uint(s0))], 1u);
    if (s1 > 0.0f) atomicAdd(&lh[score_bucket(__float_as_uint(s1))], 1u);
  }
  __syncthreads();
  u32* hseg = histG + (size_t)(img * NLV + l) * HBUCKETS;
  for (int b = tid; b < HBUCKETS; b += 256) {
    u32 v = lh[b];
    if (v) atomicAdd(&hseg[b], v);
  }
}

__device__ inline void emit_entry(float s, int a, int cls, int cx, int seg,
                                  u64* mainG, u32* mcount, u64* bndG, u32* bcount) {
  if (s <= 0.0f) return;
  u32 bits = __float_as_uint(s);
  int bk = score_bucket(bits);
  u64 key = ((u64)bits << 32) | (u64)(0xFFFFFFFFu - (u32)(a * NCLS + cls));
  if (cx < 0 || bk > cx) {
    u32 p = atomicAdd(&mcount[seg], 1u);
    if (p < 1024) mainG[(size_t)seg * 1024 + p] = key;
  } else if (bk == cx) {
    u32 p = atomicAdd(&bcount[seg], 1u);
    if (p < 4096) bndG[(size_t)seg * 4096 + p] = key;
  }
}

__global__ __launch_bounds__(256) void k_compact(const float* __restrict__ logits,
                                                 const u32* __restrict__ histG,
                                                 u64* __restrict__ mainG, u32* __restrict__ mcount,
                                                 u64* __restrict__ bndG, u32* __restrict__ bcount) {
  int img, l, a0, aend;
  block_map(blockIdx.x, img, l, a0, aend);
  int seg = img * NLV + l;
  __shared__ int sh_cx;
  int tid = threadIdx.x, wid = tid >> 6, lane = tid & 63;
  if (wid == 0) {
    int cx, cy;
    wave_find_cut(histG + (size_t)seg * HBUCKETS, c_klv[l], lane, cx, cy);
    if (lane == 0) sh_cx = cx;
  }
  __syncthreads();
  int cx = sh_cx;
  for (int a = a0 + wid; a < aend; a += 4) {
    const float* base = logits + ((size_t)img * A_TOTAL + a) * 81;
    float s0, s1;
    compute_scores(base, lane, s0, s1);
    emit_entry(s0, a, lane, cx, seg, mainG, mcount, bndG, bcount);
    if (lane < 16) emit_entry(s1, a, 64 + lane, cx, seg, mainG, mcount, bndG, bcount);
  }
}

__device__ inline void bitonic_desc(u64* s, int n) {
  for (int k = 2; k <= n; k <<= 1)
    for (int j = k >> 1; j > 0; j >>= 1) {
      __syncthreads();
      for (int i = threadIdx.x; i < n; i += blockDim.x) {
        int l = i ^ j;
        if (l > i) {
          u64 a = s[i], b = s[l];
          if (((i & k) == 0) ? (a < b) : (a > b)) { s[i] = b; s[l] = a; }
        }
      }
    }
  __syncthreads();
}

// exact per-level top-k: sort only pow2ceil(boundary count) elements
__global__ __launch_bounds__(1024) void k_refine(const u32* __restrict__ histG,
                                                 const u64* __restrict__ bndG,
                                                 const u32* __restrict__ bcount,
                                                 u64* __restrict__ mainG, u32* __restrict__ mcount) {
  int seg = blockIdx.x;
  __shared__ int sh_cx, sh_cy;
  __shared__ u64 s[4096];
  int tid = threadIdx.x, lane = tid & 63;
  if (tid < 64) {
    int cx, cy;
    wave_find_cut(histG + (size_t)seg * HBUCKETS, c_klv[seg % NLV], lane, cx, cy);
    if (lane == 0) { sh_cx = cx; sh_cy = cy; }
  }
  __syncthreads();
  if (sh_cx < 0) return;
  int m = (int)bcount[seg]; if (m > 4096) m = 4096;
  int n = 64; while (n < m) n <<= 1;
  for (int t = tid; t < n; t += 1024)
    s[t] = (t < m) ? bndG[(size_t)seg * 4096 + t] : 0ULL;
  bitonic_desc(s, n);
  int kp = sh_cy; if (kp > m) kp = m;
  int base = (int)mcount[seg];
  for (int t = tid; t < kp; t += 1024) {
    int p = base + t;
    if (p < 1024) mainG[(size_t)seg * 1024 + p] = s[t];
  }
  __syncthreads();
  if (tid == 0) {
    int nb = base + kp;
    mcount[seg] = (u32)(nb > 1024 ? 1024 : nb);
  }
}

// per-image: global cut from truncated per-level histograms, compact <2000
// above-cut, sort tiny boundary, one 2048 bitonic, decode inline.
__global__ __launch_bounds__(1024) void k_gsel(const u32* __restrict__ histG,
                                               const u64* __restrict__ mainG,
                                               const u32* __restrict__ mcount,
                                               const float4* __restrict__ priors,
                                               const float4* __restrict__ reg,
                                               float4* __restrict__ boxesG,
                                               int* __restrict__ clsG,
                                               float* __restrict__ scoreG) {
  int img = blockIdx.x;
  int tid = threadIdx.x, wid = tid >> 6, lane = tid & 63;
  __shared__ u32 H[HBUCKETS];
  __shared__ int lcx[NLV], lcy[NLV];
  __shared__ int sh_gx, sh_gy, sh_m, sh_b;
  __shared__ u64 bnd2[4096];
  __shared__ u64 sel[2048];
  if (tid == 0) { sh_m = 0; sh_b = 0; }
  if (wid < NLV) {
    int cx, cy;
    wave_find_cut(histG + (size_t)(img * NLV + wid) * HBUCKETS, c_klv[wid], lane, cx, cy);
    if (lane == 0) { lcx[wid] = cx; lcy[wid] = cy; }
  }
  __syncthreads();
  for (int b = tid; b < HBUCKETS; b += 1024) {
    u32 acc = 0;
#pragma unroll
    for (int l = 0; l < NLV; ++l) {
      u32 h = histG[(size_t)(img * NLV + l) * HBUCKETS + b];
      int cx = lcx[l];
      if (cx < 0 || b > cx) acc += h;
      else if (b == cx) acc += (u32)lcy[l];
    }
    H[b] = acc;
  }
  __syncthreads();
  if (wid == 0) {
    int gx, gy;
    wave_find_cut(H, NPRE, lane, gx, gy);
    if (lane == 0) { sh_gx = gx; sh_gy = gy; }
  }
  __syncthreads();
  int gx = sh_gx, gy = sh_gy;
  for (int l = 0; l < NLV; ++l) {
    int cnt = (int)mcount[img * NLV + l]; if (cnt > 1024) cnt = 1024;
    for (int t = tid; t < cnt; t += 1024) {
      u64 key = mainG[(size_t)(img * NLV + l) * 1024 + t];
      int b = (int)(key >> 48) - BEXP_BASE;
      b = b < 0 ? 0 : (b > HBUCKETS - 1 ? HBUCKETS - 1 : b);
      if (gx < 0 || b > gx) { int p = atomicAdd(&sh_m, 1); if (p < 2048) sel[p] = key; }
      else if (b == gx)     { int p = atomicAdd(&sh_b, 1); if (p < 4096) bnd2[p] = key; }
    }
  }
  __syncthreads();
  int msel = sh_m; if (msel > 2048) msel = 2048;
  int nb = sh_b; if (nb > 4096) nb = 4096;
  int take = 0;
  if (gx >= 0) {
    int n = 64; while (n < nb) n <<= 1;
    for (int t = tid; t < n; t += 1024) if (t >= nb) bnd2[t] = 0ULL;
    bitonic_desc(bnd2, n);
    take = gy; if (take > nb) take = nb;
    if (msel + take > 2048) take = 2048 - msel;
    for (int t = tid; t < take; t += 1024) sel[msel + t] = bnd2[t];
  }
  int tot = msel + take;
  for (int t = tid; t < 2048; t += 1024) if (t >= tot) sel[t] = 0ULL;
  bitonic_desc(sel, 2048);
  for (int t = tid; t < NPRE; t += 1024) {
    u64 key = sel[t];
    float4 bx = make_float4(0.f, 0.f, 0.f, 0.f);
    int c = -1;
    float sc = 0.f;
    if (key != 0ULL) {
      sc = __uint_as_float((u32)(key >> 32));
      u32 flat = 0xFFFFFFFFu - (u32)(key & 0xFFFFFFFFULL);
      int a = (int)(flat / NCLS);
      c = (int)(flat % NCLS);
      float4 p = priors[a];
      float4 r = reg[(size_t)img * A_TOTAL + a];
      float cx = p.x + (r.x * 0.1f) * p.z;
      float cy = p.y + (r.y * 0.1f) * p.w;
      float w = p.z * expf(r.z * 0.2f);
      float h = p.w * expf(r.w * 0.2f);
      bx.x = fminf(fmaxf(cx - w * 0.5f, 0.f), 512.f);
      bx.y = fminf(fmaxf(cy - h * 0.5f, 0.f), 512.f);
      bx.z = fminf(fmaxf(cx + w * 0.5f, 0.f), 512.f);
      bx.w = fminf(fmaxf(cy + h * 0.5f, 0.f), 512.f);
    }
    boxesG[(size_t)img * NPRE + t] = bx;
    clsG[(size_t)img * NPRE + t] = c;
    scoreG[(size_t)img * NPRE + t] = sc;
  }
}

// suppression bitmask: row i, bit j set iff j>i, same class, IoU>0.45
__global__ __launch_bounds__(256) void k_mask(const float4* __restrict__ boxesG,
                                              const int* __restrict__ clsG,
                                              u64* __restrict__ maskG) {
  __shared__ float4 lb[NPRE];
  __shared__ int lc[NPRE];
  int img = blockIdx.x / 500;
  int rb = (blockIdx.x % 500) * 4;
  for (int t = threadIdx.x; t < NPRE; t += 256) {
    lb[t] = boxesG[(size_t)img * NPRE + t];
    lc[t] = clsG[(size_t)img * NPRE + t];
  }
  __syncthreads();
  int w = threadIdx.x >> 6, lane = threadIdx.x & 63;
  int i = rb + w;
  float4 bi = lb[i];
  int ci = lc[i];
  float ai = (bi.z - bi.x) * (bi.w - bi.y);
  u64* mrow = maskG + ((size_t)img * NPRE + i) * 32;
  for (int ch = 0; ch < 32; ++ch) {
    int j = ch * 64 + lane;
    bool pred = false;
    if (j < NPRE && j > i) {
      if (lc[j] == ci) {
        float4 bj = lb[j];
        float xx1 = fmaxf(bi.x, bj.x), yy1 = fmaxf(bi.y, bj.y);
        float xx2 = fminf(bi.z, bj.z), yy2 = fminf(bi.w, bj.w);
        float ww = fmaxf(xx2 - xx1, 0.f), hh = fmaxf(yy2 - yy1, 0.f);
        float inter = ww * hh;
        float aj = (bj.z - bj.x) * (bj.w - bj.y);
        float iou = inter / fmaxf(ai + aj - inter, 1e-6f);
        pred = iou > 0.45f;
      }
    }
    u64 word = __ballot(pred);
    if (lane == 0) mrow[ch] = word;
  }
}

// greedy scan with early exit at 200 kept (later rows cannot affect earlier
// decisions), fused with final gather. Fallback: full scan + padding path.
__global__ __launch_bounds__(256) void k_scanfinal(const u64* __restrict__ maskG,
                                                   const float4* __restrict__ boxesG,
                                                   const int* __restrict__ clsG,
                                                   const float* __restrict__ scoreG,
                                                   float* __restrict__ out) {
  int img = blockIdx.x;
  int tid = threadIdx.x;
  __shared__ u64 sh_remv[32];
  __shared__ u32 keptList[216];
  __shared__ int sh_cnt, sh_done;
  __shared__ int kpref[257];
  __shared__ unsigned short S[NPRE];
  if (tid == 0) { sh_cnt = 0; sh_done = 0; }
  __syncthreads();
  if (tid < 64) {
    int lane = tid;
    int wl = lane & 31;
    const u64* M = maskG + (size_t)img * NPRE * 32;
    u64 remv = 0;
    u64 cur[16], nxt[16];
    int cnt = 0;
#pragma unroll
    for (int r = 0; r < 16; ++r) cur[r] = M[(size_t)r * 32 + wl];
    int t = 0;
    for (; t < 125; ++t) {
      if (t < 124) {
#pragma unroll
        for (int r = 0; r < 16; ++r) nxt[r] = M[(size_t)((t + 1) * 16 + r) * 32 + wl];
      }
#pragma unroll
      for (int r = 0; r < 16; ++r) {
        int i = t * 16 + r;
        u64 rm = shfl_u64(remv, i >> 6);
        if (!((rm >> (i & 63)) & 1ULL)) {   // kept (uniform across lanes)
          remv |= cur[r];
          if (lane == 0 && cnt < 216) keptList[cnt] = (u32)i;
          ++cnt;
        }
      }
#pragma unroll
      for (int r = 0; r < 16; ++r) cur[r] = nxt[r];
      if (cnt >= 200) { ++t; break; }
    }
    if (lane == 0) sh_cnt = cnt < 216 ? cnt : 216;
    if (t >= 125) {
      if (lane == 0) sh_done = 1;
      if (lane < 32) sh_remv[lane] = remv;
    }
  }
  __syncthreads();
  int nK = sh_cnt;
  if (sh_done && nK < 200) {
    // padding path: suppressed indices ascending fill tail (jax top_k stability)
    int base = tid * 8;
    bool sb[8];
    int scnt = 0;
#pragma unroll
    for (int e = 0; e < 8; ++e) {
      int i = base + e;
      bool sup = (i < NPRE) && ((sh_remv[i >> 6] >> (i & 63)) & 1ULL);
      sb[e] = sup;
      scnt += sup ? 1 : 0;
    }
    kpref[tid + 1] = scnt;
    if (tid == 0) kpref[0] = 0;
    __syncthreads();
    if (tid == 0) {
      int acc = 0;
      for (int t = 1; t <= 256; ++t) { acc += kpref[t]; kpref[t] = acc; }
    }
    __syncthreads();
    int sp = kpref[tid];
#pragma unroll
    for (int e = 0; e < 8; ++e) {
      int i = base + e;
      if (i < NPRE && sb[e]) S[sp++] = (unsigned short)i;
    }
    __syncthreads();
    if (tid < 200) {
      float fv = 0.f;
      float4 fb = make_float4(0.f, 0.f, 0.f, 0.f);
      int fc;
      if (tid < nK) {
        int idx = (int)keptList[tid];
        fv = scoreG[(size_t)img * NPRE + idx];
        fb = boxesG[(size_t)img * NPRE + idx];
        fc = clsG[(size_t)img * NPRE + idx];
      } else {
        int idx = S[tid - nK];
        fc = clsG[(size_t)img * NPRE + idx];
      }
      float* fbo = out + (size_t)img * 800 + tid * 4;
      fbo[0] = fb.x; fbo[1] = fb.y; fbo[2] = fb.z; fbo[3] = fb.w;
      out[3200 + (size_t)img * 200 + tid] = fv;
      out[4000 + (size_t)img * 200 + tid] = (float)fc;
    }
  } else {
    if (tid < 200) {
      int idx = (int)keptList[tid];
      float fv = scoreG[(size_t)img * NPRE + idx];
      float4 fb = boxesG[(size_t)img * NPRE + idx];
      int fc = clsG[(size_t)img * NPRE + idx];
      float* fbo = out + (size_t)img * 800 + tid * 4;
      fbo[0] = fb.x; fbo[1] = fb.y; fbo[2] = fb.z; fbo[3] = fb.w;
      out[3200 + (size_t)img * 200 + tid] = fv;
      out[4000 + (size_t)img * 200 + tid] = (float)fc;
    }
  }
}

extern "C" void kernel_launch(void* const* d_in, const int* in_sizes, int n_in,
                              void* d_out, int out_size, void* d_ws, size_t ws_size,
                              hipStream_t stream) {
  const float* logits = (const float*)d_in[0];
  const float4* reg = (const float4*)d_in[1];
  const float4* priors = (const float4*)d_in[2];
  char* ws = (char*)d_ws;
  u32* hist = (u32*)(ws + WS_HIST);
  u32* mcount = (u32*)(ws + WS_MCOUNT);
  u32* bcount = (u32*)(ws + WS_BCOUNT);
  u64* mainL = (u64*)(ws + WS_MAIN);
  u64* bndL = (u64*)(ws + WS_BND);
  float4* boxes = (float4*)(ws + WS_BOXES);
  int* cls = (int*)(ws + WS_CLS);
  float* score = (float*)(ws + WS_SCORE);
  u64* mask = (u64*)(ws + WS_MASK);

  hipMemsetAsync(d_ws, 0, WS_ZERO_END, stream);
  k_hist<<<NIMG * BLK_PER_IMG, 256, 0, stream>>>(logits, hist);
  k_compact<<<NIMG * BLK_PER_IMG, 256, 0, stream>>>(logits, hist, mainL, mcount, bndL, bcount);
  k_refine<<<28, 1024, 0, stream>>>(hist, bndL, bcount, mainL, mcount);
  k_gsel<<<NIMG, 1024, 0, stream>>>(hist, mainL, mcount, priors, reg, boxes, cls, score);
  k_mask<<<NIMG * 500, 256, 0, stream>>>(boxes, cls, mask);
  k_scanfinal<<<NIMG, 256, 0, stream>>>(mask, boxes, cls, score, (float*)d_out);
}